// Round 7
// baseline (302.866 us; speedup 1.0000x reference)
//
#include <hip/hip_runtime.h>
#include <math.h>

#define NN 50000
#define NE 600000
#define NG 512

typedef unsigned int u32;
typedef unsigned short u16;

typedef __attribute__((ext_vector_type(8))) short bf16x8;
typedef __attribute__((ext_vector_type(4))) float f32x4;
typedef __attribute__((ext_vector_type(4))) unsigned int u32x4;

__device__ __forceinline__ float bf2f(u16 u) {
  return __uint_as_float(((u32)u) << 16);
}
__device__ __forceinline__ u16 f2bf(float f) {
  u32 u = __float_as_uint(f);
  u32 lsb = (u >> 16) & 1u;
  u += 0x7fffu + lsb;          // RNE
  return (u16)(u >> 16);
}

// ================= fused prep: cast x, count degrees, cast+transpose weights ========
// blocks [0,12500): cast x->xb ; [12500,14844): deg_count ;
// [14844,14972): castW0 (LINEAR) ; [14972,15100): castW1 (LINEAR) ;
// [15100,15132): WlT2 (swz) ; [15132,15164): WrT2 (swz)
__global__ __launch_bounds__(256)
void prep_k(const float* __restrict__ x, u32* __restrict__ xb,
            const int* __restrict__ ei, int* __restrict__ deg,
            const float* __restrict__ Wl0, const float* __restrict__ Wr0, u16* __restrict__ WbT0,
            const float* __restrict__ Wl1, const float* __restrict__ Wr1, u16* __restrict__ WbT1,
            const float* __restrict__ Wl2, u16* __restrict__ WlT2,
            const float* __restrict__ Wr2, u16* __restrict__ WrT2) {
  int b = blockIdx.x;
  int tid = threadIdx.x;
  if (b < 12500) {
    int t = b * 256 + tid;                       // 3,200,000 exactly
    float2 v = ((const float2*)x)[t];
    xb[t] = (u32)f2bf(v.x) | ((u32)f2bf(v.y) << 16);
  } else if (b < 14844) {
    int e = (b - 12500) * 256 + tid;
    if (e < NE) atomicAdd(&deg[ei[NE + e]], 1);
  } else if (b < 15100) {
    // K=256 weight cast+transpose, LINEAR layout (read as fragments from L2)
    bool w1 = (b >= 14972);
    int t = (b - (w1 ? 14972 : 14844)) * 256 + tid;   // 128*256
    int n = t >> 8;
    int k = t & 255;
    const float* Wl = w1 ? Wl1 : Wl0;
    const float* Wr = w1 ? Wr1 : Wr0;
    float v = (k < 128) ? Wl[k * 128 + n] : Wr[(k - 128) * 128 + n];
    u16* dst = w1 ? WbT1 : WbT0;
    dst[n * 256 + k] = f2bf(v);
  } else {
    // K=128 -> 64 cols, pre-swizzled (still LDS-staged in gemm64/sage64f)
    bool wr = (b >= 15132);
    int t = (b - (wr ? 15132 : 15100)) * 256 + tid;   // 8192 = 64*128
    int n = t >> 7;
    int k = t & 127;
    const float* W = wr ? Wr2 : Wl2;
    float v = W[k * 64 + n];
    int c = k >> 3, e = k & 7;
    u16* dst = wr ? WrT2 : WlT2;
    dst[n * 128 + (((c ^ (n & 7)) << 3) | e)] = f2bf(v);
  }
}

// ================= CSR scans ========
__global__ __launch_bounds__(256)
void scan1_k(const int* __restrict__ deg, int* __restrict__ bsum) {
  __shared__ int s[256];
  int idx = blockIdx.x * 256 + threadIdx.x;
  int v = (idx < NN) ? deg[idx] : 0;
  s[threadIdx.x] = v;
  __syncthreads();
  for (int off = 128; off > 0; off >>= 1) {
    if (threadIdx.x < off) s[threadIdx.x] += s[threadIdx.x + off];
    __syncthreads();
  }
  if (threadIdx.x == 0) bsum[blockIdx.x] = s[0];
}

__global__ __launch_bounds__(256)
void scan2_k(const int* __restrict__ bsum, int* __restrict__ bofs, int* __restrict__ row_ptr) {
  __shared__ int s[256];
  int t = threadIdx.x;
  int v = (t < 196) ? bsum[t] : 0;
  s[t] = v;
  __syncthreads();
  for (int off = 1; off < 256; off <<= 1) {
    int add = (t >= off) ? s[t - off] : 0;
    __syncthreads();
    s[t] += add;
    __syncthreads();
  }
  if (t < 196) bofs[t] = s[t] - v;     // exclusive
  if (t == 0) row_ptr[NN] = NE;
}

__global__ __launch_bounds__(256)
void scan3_k(const int* __restrict__ deg, const int* __restrict__ bofs,
             int* __restrict__ row_ptr, int* __restrict__ cursor) {
  __shared__ int s[256];
  int idx = blockIdx.x * 256 + threadIdx.x;
  int t = threadIdx.x;
  int v = (idx < NN) ? deg[idx] : 0;
  s[t] = v;
  __syncthreads();
  for (int off = 1; off < 256; off <<= 1) {
    int add = (t >= off) ? s[t - off] : 0;
    __syncthreads();
    s[t] += add;
    __syncthreads();
  }
  if (idx < NN) {
    int p = bofs[blockIdx.x] + s[t] - v;
    row_ptr[idx] = p;
    cursor[idx] = p;
  }
}

__global__ __launch_bounds__(256)
void fill_k(const int* __restrict__ ei, int* __restrict__ cursor, int* __restrict__ perm) {
  int e = blockIdx.x * 256 + threadIdx.x;
  if (e >= NE) return;
  int pos = atomicAdd(&cursor[ei[NE + e]], 1);
  perm[pos] = ei[e];
}

// ===== FUSED SAGE layer (Cout=128): gather-mean -> LDS -> MFMA, one kernel =====
// 3125 blocks x 256 thr. Block owns 16 dst rows.
// Phase 1: proven gather4 inner loop (4 nodes/wave, batch-8 dwordx4, 8 KB in
//   flight, 12500 waves total); agg written bf16 to LDS, 16B-chunk XOR-swizzled.
// Phase 2: per wave a 16x32 output tile, K=256. A-agg from LDS (conflict-free
//   swizzled reads), A-x from global, B direct from LINEAR W in L2 (64 KB
//   resident; no LDS staging -> 4 KB LDS -> high occupancy so other blocks'
//   gathers overlap this block's MFMA on the same CU).
template<bool WRITE_PRE>
__global__ __launch_bounds__(256)
void sage_fused_k(const u16* __restrict__ xbin, const int* __restrict__ row_ptr,
                  const int* __restrict__ perm, const u16* __restrict__ W,
                  const float* __restrict__ bl,
                  u16* __restrict__ xb_out, float* __restrict__ out_pre) {
  __shared__ u16 ash[16 * 128];   // 4 KB agg tile, chunk-swizzled by (row&7)
  int tid = threadIdx.x;
  int wave = tid >> 6;
  int lane = tid & 63;
  int grp  = lane >> 4;           // also "quad" in phase 2
  int l16  = lane & 15;           // also "m16" in phase 2

  // ---- phase 1: gather 4 nodes for this wave ----
  int rl = wave * 4 + grp;                      // local row 0..15
  int n = blockIdx.x * 16 + rl;                 // 3125*16 = 50000 exact
  int beg = row_ptr[n];
  int cnt = row_ptr[n + 1] - beg;
  int beg_s = min(beg, NE - 1);                 // safe base for clamped reads
  int last = max(cnt - 1, 0);
  int mm = max(cnt, __shfl_xor(cnt, 16));
  int jmax = max(mm, __shfl_xor(mm, 32));       // wave-uniform loop bound
  float acc[8];
#pragma unroll
  for (int i = 0; i < 8; i++) acc[i] = 0.f;
  const u32x4* xv = (const u32x4*)xbin;         // row = 16 chunks of 16 B
  for (int base = 0; base < jmax; base += 8) {
    int idx[8];
#pragma unroll
    for (int j = 0; j < 8; j++) idx[j] = perm[beg_s + min(base + j, last)];
    u32x4 v[8];
#pragma unroll
    for (int j = 0; j < 8; j++) v[j] = xv[(size_t)idx[j] * 16 + l16];
#pragma unroll
    for (int j = 0; j < 8; j++) {
      bool live = (base + j) < cnt;
#pragma unroll
      for (int w = 0; w < 4; w++) {
        u32 u = v[j][w];
        acc[2 * w]     += live ? __uint_as_float(u << 16) : 0.f;
        acc[2 * w + 1] += live ? __uint_as_float(u & 0xffff0000u) : 0.f;
      }
    }
  }
  {
    float inv = 1.0f / fmaxf((float)cnt, 1.0f);
    u32x4 o;
#pragma unroll
    for (int w = 0; w < 4; w++)
      o[w] = (u32)f2bf(acc[2 * w] * inv) | ((u32)f2bf(acc[2 * w + 1] * inv) << 16);
    ((u32x4*)ash)[rl * 16 + (l16 ^ (rl & 7))] = o;   // swizzled chunk store
  }
  __syncthreads();

  // ---- phase 2: 16 rows x 32 cols per wave, K=256 ----
  int quad = grp;
  int m16  = l16;
  int c0 = wave * 32;
  int r0 = blockIdx.x * 16;
  int swz = m16 & 7;

  bf16x8 a[8];
#pragma unroll
  for (int j = 0; j < 4; j++)      // agg half (K 0..127) from LDS, unswizzle
    a[j] = *(const bf16x8*)(ash + m16 * 128 + (((j * 4 + quad) ^ swz) << 3));
  {
    const u16* px = xbin + (size_t)(r0 + m16) * 128 + quad * 8;
#pragma unroll
    for (int j = 0; j < 4; j++)    // x half (K 128..255) from global
      a[4 + j] = *(const bf16x8*)(px + j * 32);
  }

  f32x4 acc2[2];
  acc2[0] = (f32x4){0.f, 0.f, 0.f, 0.f};
  acc2[1] = (f32x4){0.f, 0.f, 0.f, 0.f};
  const u16* brow0 = W + (size_t)(c0 + m16) * 256 + quad * 8;
  const u16* brow1 = W + (size_t)(c0 + 16 + m16) * 256 + quad * 8;
#pragma unroll
  for (int ks = 0; ks < 8; ks++) {
    bf16x8 b0 = *(const bf16x8*)(brow0 + ks * 32);
    bf16x8 b1 = *(const bf16x8*)(brow1 + ks * 32);
    acc2[0] = __builtin_amdgcn_mfma_f32_16x16x32_bf16(a[ks], b0, acc2[0], 0, 0, 0);
    acc2[1] = __builtin_amdgcn_mfma_f32_16x16x32_bf16(a[ks], b1, acc2[1], 0, 0, 0);
  }

  float bv0 = bl[c0 + m16];
  float bv1 = bl[c0 + 16 + m16];
  int rbase = r0 + quad * 4;
#pragma unroll
  for (int r = 0; r < 4; r++) {
    int row = rbase + r;                         // always < 50000
    float v0 = acc2[0][r] + bv0;
    float v1 = acc2[1][r] + bv1;
    if (WRITE_PRE) {
      out_pre[(size_t)row * 128 + c0 + m16]      = v0;
      out_pre[(size_t)row * 128 + c0 + 16 + m16] = v1;
    }
    xb_out[(size_t)row * 128 + c0 + m16]      = f2bf(fmaxf(v0, 0.f));
    xb_out[(size_t)row * 128 + c0 + 16 + m16] = f2bf(fmaxf(v1, 0.f));
  }
}

// ===== gather-mean (64 ch rows = 128 B = ONE cache line/edge): 8 nodes/wave =====
__global__ __launch_bounds__(256)
void gather8_k(const u16* __restrict__ yb, const int* __restrict__ row_ptr,
               const int* __restrict__ perm, u16* __restrict__ aggy) {
  int wave = threadIdx.x >> 6;
  int lane = threadIdx.x & 63;
  int grp  = lane >> 3;               // 0..7
  int li   = lane & 7;
  int n = (blockIdx.x * 4 + wave) * 8 + grp;     // 1563*4*8 = 50016 (tail clamped)
  int ns = min(n, NN - 1);
  int beg = row_ptr[ns];
  int cnt = row_ptr[ns + 1] - beg;
  int beg_s = min(beg, NE - 1);
  int last = max(cnt - 1, 0);
  int m = max(cnt, __shfl_xor(cnt, 8));
  m = max(m, __shfl_xor(m, 16));
  int jmax = max(m, __shfl_xor(m, 32));          // wave-uniform loop bound
  float acc[8];
#pragma unroll
  for (int i = 0; i < 8; i++) acc[i] = 0.f;
  const u32x4* xv = (const u32x4*)yb;            // row = 8 chunks of 16 B
  for (int base = 0; base < jmax; base += 8) {
    int idx[8];
#pragma unroll
    for (int j = 0; j < 8; j++) idx[j] = perm[beg_s + min(base + j, last)];
    u32x4 v[8];
#pragma unroll
    for (int j = 0; j < 8; j++) v[j] = xv[(size_t)idx[j] * 8 + li];
#pragma unroll
    for (int j = 0; j < 8; j++) {
      bool live = (base + j) < cnt;
#pragma unroll
      for (int w = 0; w < 4; w++) {
        u32 u = v[j][w];
        acc[2 * w]     += live ? __uint_as_float(u << 16) : 0.f;
        acc[2 * w + 1] += live ? __uint_as_float(u & 0xffff0000u) : 0.f;
      }
    }
  }
  float inv = 1.0f / fmaxf((float)cnt, 1.0f);
  u32x4 o;
#pragma unroll
  for (int w = 0; w < 4; w++)
    o[w] = (u32)f2bf(acc[2 * w] * inv) | ((u32)f2bf(acc[2 * w + 1] * inv) << 16);
  if (n < NN) ((u32x4*)aggy)[(size_t)n * 8 + li] = o;
}

// ===== merged pool + gemm64 (both read xb2, independent) =====
// blocks [0,NG): graph pooling ; [NG, NG+782): y2 = xb2 @ Wl2
__global__ __launch_bounds__(256)
void post_k(const u16* __restrict__ xb2, const int* __restrict__ cluster,
            float* __restrict__ g, const u16* __restrict__ WlT2,
            u16* __restrict__ yb) {
  __shared__ u16 wsh[64 * 128];         // 16 KB (gemm blocks); pool reuses as float
  int tid = threadIdx.x;
  if (blockIdx.x < NG) {
    // ---- pooling: 256 thr, odd/even node split + LDS combine ----
    float* sh = (float*)wsh;
    int gid = blockIdx.x;
    int ch = tid & 127;
    int half = tid >> 7;
    int lo = 0, hi = NN;
    while (lo < hi) { int mid = (lo + hi) >> 1; if (cluster[mid] < gid) lo = mid + 1; else hi = mid; }
    int beg = lo;
    hi = NN;
    while (lo < hi) { int mid = (lo + hi) >> 1; if (cluster[mid] < gid + 1) lo = mid + 1; else hi = mid; }
    int end = lo;
    float s0 = 0.f, s1 = 0.f;
    int n = beg + half;
    for (; n + 2 < end; n += 4) {
      s0 += bf2f(xb2[(size_t)n * 128 + ch]);
      s1 += bf2f(xb2[(size_t)(n + 2) * 128 + ch]);
    }
    if (n < end) s0 += bf2f(xb2[(size_t)n * 128 + ch]);
    sh[tid] = s0 + s1;
    __syncthreads();
    if (tid < 128) {
      float s = sh[tid] + sh[tid + 128];
      g[gid * 128 + tid] = s / fmaxf((float)(end - beg), 1.0f);
    }
    return;
  }
  // ---- gemm64: y2 = xb2 @ Wl2 (K=128 -> 64 cols, bf16 out) ----
  int bid = blockIdx.x - NG;
  {
    const u32x4* gw = (const u32x4*)WlT2;
    u32x4* l = (u32x4*)wsh;
#pragma unroll
    for (int i = 0; i < 4; i++)
      l[tid + i * 256] = gw[tid + i * 256];
  }
  __syncthreads();

  int wave = tid >> 6;
  int lane = tid & 63;
  int quad = lane >> 4;
  int m16  = lane & 15;
  int r0 = bid * 64 + wave * 16;

  int rowA = min(r0 + m16, NN - 1);
  const u16* px = xb2 + (size_t)rowA * 128 + quad * 8;
  bf16x8 a[4];
#pragma unroll
  for (int j = 0; j < 4; j++) a[j] = *(const bf16x8*)(px + j * 32);

  f32x4 acc[4];
#pragma unroll
  for (int nt = 0; nt < 4; nt++) acc[nt] = (f32x4){0.f, 0.f, 0.f, 0.f};

  int swz = m16 & 7;
#pragma unroll
  for (int ks = 0; ks < 4; ks++) {
#pragma unroll
    for (int nt = 0; nt < 4; nt++) {
      const u16* bp = wsh + (nt * 16 + m16) * 128 + (((ks * 4 + quad) ^ swz) << 3);
      bf16x8 b = *(const bf16x8*)bp;
      acc[nt] = __builtin_amdgcn_mfma_f32_16x16x32_bf16(a[ks], b, acc[nt], 0, 0, 0);
    }
  }

  int rbase = r0 + quad * 4;
#pragma unroll
  for (int r = 0; r < 4; r++) {
    int row = rbase + r;
    if (row < NN) {
#pragma unroll
      for (int nt = 0; nt < 4; nt++)
        yb[(size_t)row * 64 + nt * 16 + m16] = f2bf(acc[nt][r]);
    }
  }
}

// ===== final layer: out = log_softmax(aggY + bl2 + xb2 @ Wr2) =====
__global__ __launch_bounds__(256)
void sage64f_k(const u16* __restrict__ aggy, const u16* __restrict__ xbin,
               const u16* __restrict__ WT, const float* __restrict__ bl,
               float* __restrict__ out) {
  __shared__ u16 wsh[64 * 128];         // 16 KB
  int tid = threadIdx.x;
  {
    const u32x4* g = (const u32x4*)WT;
    u32x4* l = (u32x4*)wsh;
#pragma unroll
    for (int i = 0; i < 4; i++)
      l[tid + i * 256] = g[tid + i * 256];
  }
  __syncthreads();

  int wave = tid >> 6;
  int lane = tid & 63;
  int quad = lane >> 4;
  int m16  = lane & 15;
  int r0 = blockIdx.x * 64 + wave * 16;

  int rowA = min(r0 + m16, NN - 1);
  const u16* px = xbin + (size_t)rowA * 128 + quad * 8;
  bf16x8 a[4];
#pragma unroll
  for (int j = 0; j < 4; j++) a[j] = *(const bf16x8*)(px + j * 32);

  f32x4 acc[4];
#pragma unroll
  for (int nt = 0; nt < 4; nt++) acc[nt] = (f32x4){0.f, 0.f, 0.f, 0.f};

  int swz = m16 & 7;
#pragma unroll
  for (int ks = 0; ks < 4; ks++) {
#pragma unroll
    for (int nt = 0; nt < 4; nt++) {
      const u16* bp = wsh + (nt * 16 + m16) * 128 + (((ks * 4 + quad) ^ swz) << 3);
      bf16x8 b = *(const bf16x8*)bp;
      acc[nt] = __builtin_amdgcn_mfma_f32_16x16x32_bf16(a[ks], b, acc[nt], 0, 0, 0);
    }
  }

  float bv[4];
#pragma unroll
  for (int nt = 0; nt < 4; nt++) bv[nt] = bl[nt * 16 + m16];

  int rbase = r0 + quad * 4;
#pragma unroll
  for (int r = 0; r < 4; r++) {
    int row = rbase + r;
    int rs = min(row, NN - 1);
    float v0 = acc[0][r] + bv[0] + bf2f(aggy[(size_t)rs * 64 + m16]);
    float v1 = acc[1][r] + bv[1] + bf2f(aggy[(size_t)rs * 64 + 16 + m16]);
    float v2 = acc[2][r] + bv[2] + bf2f(aggy[(size_t)rs * 64 + 32 + m16]);
    float v3 = acc[3][r] + bv[3] + bf2f(aggy[(size_t)rs * 64 + 48 + m16]);
    float m = fmaxf(fmaxf(v0, v1), fmaxf(v2, v3));
#pragma unroll
    for (int mk = 1; mk <= 8; mk <<= 1) m = fmaxf(m, __shfl_xor(m, mk));
    float s = __expf(v0 - m) + __expf(v1 - m) + __expf(v2 - m) + __expf(v3 - m);
#pragma unroll
    for (int mk = 1; mk <= 8; mk <<= 1) s += __shfl_xor(s, mk);
    float ls = m + __logf(s);
    if (row < NN) {
      float* orow = out + (size_t)row * 64;
      orow[m16]      = v0 - ls;
      orow[16 + m16] = v1 - ls;
      orow[32 + m16] = v2 - ls;
      orow[48 + m16] = v3 - ls;
    }
  }
}

extern "C" void kernel_launch(void* const* d_in, const int* in_sizes, int n_in,
                              void* d_out, int out_size, void* d_ws, size_t ws_size,
                              hipStream_t stream) {
  const float* x   = (const float*)d_in[0];
  const int*   ei  = (const int*)d_in[1];
  const int*   cl  = (const int*)d_in[2];
  const float* Wl0 = (const float*)d_in[3];
  const float* bl0 = (const float*)d_in[4];
  const float* Wr0 = (const float*)d_in[5];
  const float* Wl1 = (const float*)d_in[6];
  const float* bl1 = (const float*)d_in[7];
  const float* Wr1 = (const float*)d_in[8];
  const float* Wl2 = (const float*)d_in[9];
  const float* bl2 = (const float*)d_in[10];
  const float* Wr2 = (const float*)d_in[11];
  float* out = (float*)d_out;

  char* ws = (char*)d_ws;
  u16*   xb0     = (u16*)  (ws);                  // 12,800,000 B (bf16 of x)
  u16*   xb1     = (u16*)  (ws + 12800000);       // 12,800,000 B (relu layer0)
  u16*   xb2     = (u16*)  (ws + 25600000);       // 12,800,000 B (relu layer1)
  u16*   y2      = (u16*)  (ws + 38400000);       //  6,400,000 B (xb2 @ Wl2, bf16)
  u16*   aggy    = (u16*)  (ws + 44800000);       //  6,400,000 B
  u16*   WbT0    = (u16*)  (ws + 51200000);       //     65,536 B (LINEAR, K=256)
  u16*   WbT1    = (u16*)  (ws + 51265536);       //     65,536 B (LINEAR)
  u16*   WlT2    = (u16*)  (ws + 51331072);       //     16,384 B (pre-swizzled, K=128)
  u16*   WrT2    = (u16*)  (ws + 51347456);       //     16,384 B
  int*   deg     = (int*)  (ws + 51363840);       //    200,000 B
  int*   row_ptr = (int*)  (ws + 51564032);       //    200,004 B (+pad)
  int*   cursor  = (int*)  (ws + 51764736);       //    200,000 B
  int*   perm    = (int*)  (ws + 51964736);       //  2,400,000 B
  int*   bsum    = (int*)  (ws + 54364736);       //        784 B
  int*   bofs    = (int*)  (ws + 54365568);       //        784 B
  // total ~54.4 MB

  float* out_lsm = out;            // [50000,64]
  float* out_pre = out + 3200000;  // [50000,128]
  float* out_g   = out + 9600000;  // [512,128]

  // ---- fused prep (cast x, deg count, all weight casts) ----
  hipMemsetAsync(deg, 0, 200000, stream);
  prep_k<<<15164, 256, 0, stream>>>(x, (u32*)xb0, ei, deg,
                                    Wl0, Wr0, WbT0, Wl1, Wr1, WbT1,
                                    Wl2, WlT2, Wr2, WrT2);

  // ---- CSR scans + fill ----
  scan1_k<<<196, 256, 0, stream>>>(deg, bsum);
  scan2_k<<<1, 256, 0, stream>>>(bsum, bofs, row_ptr);
  scan3_k<<<196, 256, 0, stream>>>(deg, bofs, row_ptr, cursor);
  fill_k<<<2344, 256, 0, stream>>>(ei, cursor, perm);

  // ---- layer 0 (fused gather+GEMM) ----
  sage_fused_k<false><<<3125, 256, 0, stream>>>(xb0, row_ptr, perm, WbT0, bl0, xb1, nullptr);

  // ---- layer 1 (fused; pre-relu f32 straight to d_out) ----
  sage_fused_k<true><<<3125, 256, 0, stream>>>(xb1, row_ptr, perm, WbT1, bl1, xb2, out_pre);

  // ---- pooling + y2 GEMM (merged, both read xb2) ----
  post_k<<<NG + 782, 256, 0, stream>>>(xb2, cl, out_g, WlT2, y2);

  // ---- final layer via linearity: aggY = gather-mean(y2);
  //      out = log_softmax(aggY + bl2 + xb2@Wr2) ----
  gather8_k<<<1563, 256, 0, stream>>>(y2, row_ptr, perm, aggy);
  sage64f_k<<<782, 256, 0, stream>>>(aggy, xb2, WrT2, bl2, out_lsm);
}